// Round 1
// baseline (856.875 us; speedup 1.0000x reference)
//
#include <hip/hip_runtime.h>
#include <math.h>

// Problem constants
#define BB 16
#define NN 8192
#define FF 512
#define EE 128
#define CC 100

// ws layout (floats)
// Pt:     [EE][FF]       = 65536   @ 0
// qp:     [BB][EE]       = 2048    @ 65536
// scores: [BB][NN]       = 131072  @ 67584
// stats:  max[16],inv[16]= 32      @ 198656
#define WS_PT 0
#define WS_QP 65536
#define WS_SC 67584
#define WS_ST 198656

// ---------------- K0a: Pt[e][f] = W[f][e] * sigmoid(mask[e]) ----------------
__global__ __launch_bounds__(256) void k_prep(const float* __restrict__ W,
                                              const float* __restrict__ mask,
                                              float* __restrict__ Pt) {
    int tid = blockIdx.x * 256 + threadIdx.x;            // grid 64*256 = 16384
    for (int p = tid; p < EE * FF; p += 64 * 256) {
        int e = p >> 9;          // p / FF
        int f = p & (FF - 1);
        float m = 1.f / (1.f + expf(-mask[e]));
        Pt[p] = W[f * EE + e] * m;
    }
}

// ---------------- K0b: q'[b][e] = sigmoid(mask[e]) * sum_f x[b][f] W[f][e] --
__global__ __launch_bounds__(256) void k_q(const float* __restrict__ x,
                                           const float* __restrict__ W,
                                           const float* __restrict__ mask,
                                           float* __restrict__ qp) {
    int b = blockIdx.x;
    int t = threadIdx.x;                                 // 256
    __shared__ float xl[FF];
    __shared__ float qred[256];
    xl[t]       = x[b * FF + t];
    xl[t + 256] = x[b * FF + t + 256];
    __syncthreads();
    int e = t & 127, grp = t >> 7;
    float s = 0.f;
    int f0 = grp * 256;
    for (int f = f0; f < f0 + 256; ++f) s += xl[f] * W[f * EE + e];
    qred[grp * 128 + e] = s;
    __syncthreads();
    if (t < 128) {
        float m = 1.f / (1.f + expf(-mask[t]));
        qp[b * EE + t] = (qred[t] + qred[128 + t]) * m;
    }
}

// ---------------- K1: fused scores GEMM --------------------------------------
// scores'[b][n] = sum_e (2 q'[b][e] - s'[n][e]) * s'[n][e],
// s'[n][e] = sum_f sx[b][n][f] * Pt[e][f]
// Block: 256 thr, tile 128 rows x 128 cols, K-chunk 32, 8x8 reg blocking.
#define KC 32
#define LDP 34   // padded LDS leading dim (2-way bank conflicts only)
__global__ __launch_bounds__(256) void k_scores(const float* __restrict__ sx,
                                                const float* __restrict__ Pt,
                                                const float* __restrict__ qp,
                                                float* __restrict__ scores) {
    __shared__ float Al[128 * LDP];
    __shared__ float Pl[128 * LDP];
    const int b = blockIdx.y;
    const int n0 = blockIdx.x * 128;
    const int t = threadIdx.x;
    const int cg = t & 15, rg = t >> 4;
    const int r0 = rg * 8, c0 = cg * 8;

    float qv[8];
#pragma unroll
    for (int j = 0; j < 8; ++j) qv[j] = qp[b * EE + c0 + j];

    float acc[8][8];
#pragma unroll
    for (int i = 0; i < 8; ++i)
#pragma unroll
        for (int j = 0; j < 8; ++j) acc[i][j] = 0.f;

    const float* A0 = sx + ((size_t)b * NN + n0) * FF;

    for (int kc = 0; kc < FF / KC; ++kc) {
        const int k0 = kc * KC;
        __syncthreads();
        // stage A tile (128 x 32) and Pt tile (128 x 32)
#pragma unroll
        for (int j = 0; j < 4; ++j) {
            int q = t + 256 * j;          // float4 index 0..1023
            int row = q >> 3;             // 8 float4 per row
            int kq = q & 7;
            const float4 va = *(const float4*)(A0 + (size_t)row * FF + k0 + kq * 4);
            float* da = &Al[row * LDP + kq * 4];
            ((float2*)da)[0] = make_float2(va.x, va.y);
            ((float2*)da)[1] = make_float2(va.z, va.w);
            const float4 vp = *(const float4*)(Pt + row * FF + k0 + kq * 4);
            float* dp = &Pl[row * LDP + kq * 4];
            ((float2*)dp)[0] = make_float2(vp.x, vp.y);
            ((float2*)dp)[1] = make_float2(vp.z, vp.w);
        }
        __syncthreads();
        // compute
#pragma unroll 4
        for (int kp = 0; kp < KC / 2; ++kp) {
            float2 av[8], pv[8];
#pragma unroll
            for (int i = 0; i < 8; ++i)
                av[i] = *(const float2*)&Al[(r0 + i) * LDP + kp * 2];
#pragma unroll
            for (int j = 0; j < 8; ++j)
                pv[j] = *(const float2*)&Pl[(c0 + j) * LDP + kp * 2];
#pragma unroll
            for (int i = 0; i < 8; ++i)
#pragma unroll
                for (int j = 0; j < 8; ++j)
                    acc[i][j] += av[i].x * pv[j].x + av[i].y * pv[j].y;
        }
    }

    // epilogue: per-row partial score over this thread's 8 columns
    float part[8];
#pragma unroll
    for (int i = 0; i < 8; ++i) {
        float s = 0.f;
#pragma unroll
        for (int j = 0; j < 8; ++j)
            s += (2.f * qv[j] - acc[i][j]) * acc[i][j];
        part[i] = s;
    }
    __syncthreads();
    float* red = Al;                       // overlay reduction buffer [128][17]
#pragma unroll
    for (int i = 0; i < 8; ++i) red[(r0 + i) * 17 + cg] = part[i];
    __syncthreads();
    if (t < 128) {
        float s = 0.f;
#pragma unroll
        for (int c = 0; c < 16; ++c) s += red[t * 17 + c];
        scores[b * NN + n0 + t] = s;
    }
}

// ---------------- K2: per-b softmax stats + zero out -------------------------
__global__ __launch_bounds__(256) void k_stats(const float* __restrict__ scores,
                                               float* __restrict__ stats,
                                               float* __restrict__ out) {
    int b = blockIdx.x;
    int t = threadIdx.x;
    __shared__ float red[8];
    int wave = t >> 6;
    float m = -3.4e38f;
    for (int i = t; i < NN; i += 256) m = fmaxf(m, scores[b * NN + i]);
#pragma unroll
    for (int off = 32; off > 0; off >>= 1) m = fmaxf(m, __shfl_xor(m, off));
    if ((t & 63) == 0) red[wave] = m;
    __syncthreads();
    float mb = fmaxf(fmaxf(red[0], red[1]), fmaxf(red[2], red[3]));
    float s = 0.f;
    for (int i = t; i < NN; i += 256) s += expf(scores[b * NN + i] - mb);
#pragma unroll
    for (int off = 32; off > 0; off >>= 1) s += __shfl_xor(s, off);
    if ((t & 63) == 0) red[4 + wave] = s;
    __syncthreads();
    if (t == 0) {
        float tot = red[4] + red[5] + red[6] + red[7];
        stats[b] = mb;
        stats[16 + b] = 1.f / tot;
    }
    if (t < CC) out[b * CC + t] = 0.f;
}

// ---------------- K3: out[b][c] += sum_n p_n * y[b][n][c] --------------------
__global__ __launch_bounds__(256) void k_out(const float* __restrict__ scores,
                                             const float* __restrict__ sy,
                                             const float* __restrict__ stats,
                                             float* __restrict__ out) {
    int b = blockIdx.y;
    int n0 = blockIdx.x * 512;
    int t = threadIdx.x;
    __shared__ float pl[512];
    float mb = stats[b], inv = stats[16 + b];
    for (int i = t; i < 512; i += 256)
        pl[i] = expf(scores[b * NN + n0 + i] - mb) * inv;
    __syncthreads();
    int c = t & 127, half = t >> 7;
    if (c < CC) {
        float acc = 0.f;
        const float* Y = sy + ((size_t)b * NN + n0 + half * 256) * CC;
        for (int i = 0; i < 256; ++i) acc += pl[half * 256 + i] * Y[(size_t)i * CC + c];
        atomicAdd(&out[b * CC + c], acc);
    }
}

extern "C" void kernel_launch(void* const* d_in, const int* in_sizes, int n_in,
                              void* d_out, int out_size, void* d_ws, size_t ws_size,
                              hipStream_t stream) {
    const float* x    = (const float*)d_in[0];   // (16,512)
    const float* sx   = (const float*)d_in[1];   // (16,8192,512)
    const float* sy   = (const float*)d_in[2];   // (16,8192,100)
    const float* W    = (const float*)d_in[3];   // (512,128)
    const float* mask = (const float*)d_in[4];   // (128,)
    float* out = (float*)d_out;
    float* ws = (float*)d_ws;
    float* Pt     = ws + WS_PT;
    float* qp     = ws + WS_QP;
    float* scores = ws + WS_SC;
    float* stats  = ws + WS_ST;

    k_prep  <<<64, 256, 0, stream>>>(W, mask, Pt);
    k_q     <<<BB, 256, 0, stream>>>(x, W, mask, qp);
    k_scores<<<dim3(NN / 128, BB), 256, 0, stream>>>(sx, Pt, qp, scores);
    k_stats <<<BB, 256, 0, stream>>>(scores, stats, out);
    k_out   <<<dim3(NN / 512, BB), 256, 0, stream>>>(scores, sy, stats, out);
}

// Round 2
// 476.060 us; speedup vs baseline: 1.7999x; 1.7999x over previous
//
#include <hip/hip_runtime.h>
#include <math.h>

// Problem constants
#define BB 16
#define NN 8192
#define FF 512
#define EE 128
#define CC 100

typedef __attribute__((ext_vector_type(8))) short short8;
typedef __attribute__((ext_vector_type(4))) float f32x4;

// ws layout (bytes)
// Pth:    [EE][FF] bf16 = 131072 @ 0
// Ptl:    [EE][FF] bf16 = 131072 @ 131072
// qp:     [BB][EE] f32  = 8192   @ 262144
// scores: [BB][NN] f32  = 524288 @ 270336
// stats:  max[16],inv[16] f32    @ 794624
#define WSB_PTH 0
#define WSB_PTL 131072
#define WSB_QP  262144
#define WSB_SC  270336
#define WSB_ST  794624

__device__ inline ushort bf16_rne(float x) {
    uint u = __float_as_uint(x);
    uint r = u + 0x7FFFu + ((u >> 16) & 1u);
    return (ushort)(r >> 16);
}

// ---------------- K0a: Pt[e][f] = W[f][e]*sigmoid(mask[e]), split hi/lo bf16
__global__ __launch_bounds__(256) void k_prep2(const float* __restrict__ W,
                                               const float* __restrict__ mask,
                                               ushort* __restrict__ Pth,
                                               ushort* __restrict__ Ptl) {
    int tid = blockIdx.x * 256 + threadIdx.x;            // grid 64
    for (int p = tid; p < EE * FF; p += 64 * 256) {
        int e = p >> 9, f = p & (FF - 1);
        float m = 1.f / (1.f + expf(-mask[e]));
        float v = W[f * EE + e] * m;
        ushort h = bf16_rne(v);
        float hf = __uint_as_float(((uint)h) << 16);
        ushort l = bf16_rne(v - hf);
        Pth[p] = h;
        Ptl[p] = l;
    }
}

// ---------------- K0b: q'[b][e] = sigmoid(mask[e]) * sum_f x[b][f] W[f][e] --
__global__ __launch_bounds__(256) void k_q(const float* __restrict__ x,
                                           const float* __restrict__ W,
                                           const float* __restrict__ mask,
                                           float* __restrict__ qp) {
    int b = blockIdx.x;
    int t = threadIdx.x;
    __shared__ float xl[FF];
    __shared__ float qred[256];
    xl[t]       = x[b * FF + t];
    xl[t + 256] = x[b * FF + t + 256];
    __syncthreads();
    int e = t & 127, grp = t >> 7;
    float s = 0.f;
    int f0 = grp * 256;
    for (int f = f0; f < f0 + 256; ++f) s += xl[f] * W[f * EE + e];
    qred[grp * 128 + e] = s;
    __syncthreads();
    if (t < 128) {
        float m = 1.f / (1.f + expf(-mask[t]));
        qp[b * EE + t] = (qred[t] + qred[128 + t]) * m;
    }
}

// ---------------- K1: fused MFMA scores kernel -------------------------------
// Per block: 128 support rows x all 128 e-cols, K=512 in chunks of 64.
// 4 waves in 2x2; wave = 64 rows x 64 cols = 4x4 fragment tiles of 16x16.
// acc = ah*bh + ah*bl + al*bh (bf16 split, f32 accumulate).
__global__ __launch_bounds__(256, 2) void k_scores(const float* __restrict__ sx,
                                                   const ushort* __restrict__ Pth,
                                                   const ushort* __restrict__ Ptl,
                                                   const float* __restrict__ qp,
                                                   float* __restrict__ scores) {
    // LDS: Ah[128][64] Al[128][64] Ph[128][64] Pl[128][64], each 16KB bf16
    __shared__ __align__(16) char smem[65536];
    char* AhB = smem;
    char* AlB = smem + 16384;
    char* PhB = smem + 32768;
    char* PlB = smem + 49152;

    const int b  = blockIdx.y;
    const int n0 = blockIdx.x * 128;
    const int t  = threadIdx.x;
    const int lane = t & 63;
    const int w  = t >> 6;
    const int wr = w >> 1, wc = w & 1;       // wave tile: rows wr*64.., cols wc*64..
    const int l15 = lane & 15, l4 = lane >> 4;

    f32x4 acc[4][4];
#pragma unroll
    for (int i = 0; i < 4; ++i)
#pragma unroll
        for (int j = 0; j < 4; ++j) acc[i][j] = (f32x4){0.f, 0.f, 0.f, 0.f};

    const float* A0 = sx + ((size_t)b * NN + n0) * FF;

    for (int kc = 0; kc < FF / 64; ++kc) {
        const int kc0 = kc * 64;
        __syncthreads();
        // ---- stage A (f32 -> bf16 hi/lo), 128x64 ----
#pragma unroll
        for (int m = 0; m < 8; ++m) {
            int idx = t + 256 * m;            // float4 id, 0..2047
            int row = idx >> 4;               // 16 float4 per row
            int kq  = idx & 15;
            const float4 va = *(const float4*)(A0 + (size_t)row * FF + kc0 + kq * 4);
            uint u0 = __float_as_uint(va.x), u1 = __float_as_uint(va.y);
            uint u2 = __float_as_uint(va.z), u3 = __float_as_uint(va.w);
            uint2 hv = make_uint2((u0 >> 16) | (u1 & 0xFFFF0000u),
                                  (u2 >> 16) | (u3 & 0xFFFF0000u));
            float l0 = va.x - __uint_as_float(u0 & 0xFFFF0000u);
            float l1 = va.y - __uint_as_float(u1 & 0xFFFF0000u);
            float l2 = va.z - __uint_as_float(u2 & 0xFFFF0000u);
            float l3 = va.w - __uint_as_float(u3 & 0xFFFF0000u);
            uint2 lv = make_uint2((__float_as_uint(l0) >> 16) | (__float_as_uint(l1) & 0xFFFF0000u),
                                  (__float_as_uint(l2) >> 16) | (__float_as_uint(l3) & 0xFFFF0000u));
            uint off = (uint)(row * 128 + kq * 8) ^ ((uint)(row & 7) << 4);
            *(uint2*)(AhB + off) = hv;
            *(uint2*)(AlB + off) = lv;
        }
        // ---- stage Pt hi/lo (bf16 direct copy), 128x64 each ----
#pragma unroll
        for (int m = 0; m < 4; ++m) {
            int idx = t + 256 * m;            // uint4 id, 0..1023
            int row = idx >> 3;               // 8 uint4 per row
            int kq  = idx & 7;
            uint off = (uint)(row * 128 + kq * 16) ^ ((uint)(row & 7) << 4);
            *(uint4*)(PhB + off) = *(const uint4*)(Pth + (size_t)row * FF + kc0 + kq * 8);
            *(uint4*)(PlB + off) = *(const uint4*)(Ptl + (size_t)row * FF + kc0 + kq * 8);
        }
        __syncthreads();
        // ---- compute: 2 k-steps of K=32 ----
#pragma unroll
        for (int ks = 0; ks < 2; ++ks) {
            const int kByte = (ks * 32 + l4 * 8) * 2;
            short8 aH[4], aL[4];
#pragma unroll
            for (int i = 0; i < 4; ++i) {
                int row = wr * 64 + i * 16 + l15;
                uint off = (uint)(row * 128 + kByte) ^ ((uint)(row & 7) << 4);
                aH[i] = *(const short8*)(AhB + off);
                aL[i] = *(const short8*)(AlB + off);
            }
#pragma unroll
            for (int j = 0; j < 4; ++j) {
                int er = wc * 64 + j * 16 + l15;
                uint off = (uint)(er * 128 + kByte) ^ ((uint)(er & 7) << 4);
                short8 bH = *(const short8*)(PhB + off);
                short8 bL = *(const short8*)(PlB + off);
#pragma unroll
                for (int i = 0; i < 4; ++i)
                    acc[i][j] = __builtin_amdgcn_mfma_f32_16x16x32_bf16(aH[i], bH, acc[i][j], 0, 0, 0);
#pragma unroll
                for (int i = 0; i < 4; ++i)
                    acc[i][j] = __builtin_amdgcn_mfma_f32_16x16x32_bf16(aH[i], bL, acc[i][j], 0, 0, 0);
#pragma unroll
                for (int i = 0; i < 4; ++i)
                    acc[i][j] = __builtin_amdgcn_mfma_f32_16x16x32_bf16(aL[i], bH, acc[i][j], 0, 0, 0);
            }
        }
    }

    // ---- epilogue: score[n] = sum_e (2 q[e] - s[n][e]) * s[n][e] ----
    float qv[4];
#pragma unroll
    for (int j = 0; j < 4; ++j) qv[j] = qp[b * EE + wc * 64 + j * 16 + l15];

    __syncthreads();                         // all MFMA LDS reads done
    float* red = (float*)smem;               // [2][128]
#pragma unroll
    for (int i = 0; i < 4; ++i) {
        float p[4];
#pragma unroll
        for (int r = 0; r < 4; ++r) {
            float s = 0.f;
#pragma unroll
            for (int j = 0; j < 4; ++j) {
                float sv = acc[i][j][r];
                s += (2.f * qv[j] - sv) * sv;
            }
            p[r] = s;
        }
#pragma unroll
        for (int off = 1; off < 16; off <<= 1)
#pragma unroll
            for (int r = 0; r < 4; ++r) p[r] += __shfl_xor(p[r], off);
        if (l15 == 0) {
#pragma unroll
            for (int r = 0; r < 4; ++r)
                red[wc * 128 + wr * 64 + i * 16 + l4 * 4 + r] = p[r];
        }
    }
    __syncthreads();
    if (t < 128) scores[b * NN + n0 + t] = red[t] + red[128 + t];
}

// ---------------- K2: per-b softmax stats + zero out -------------------------
__global__ __launch_bounds__(1024) void k_stats(const float* __restrict__ scores,
                                                float* __restrict__ stats,
                                                float* __restrict__ out) {
    int b = blockIdx.x;
    int t = threadIdx.x;
    __shared__ float red_m[16];
    __shared__ float red_s[16];
    float m = -3.4e38f;
    for (int i = t; i < NN; i += 1024) m = fmaxf(m, scores[b * NN + i]);
#pragma unroll
    for (int off = 32; off > 0; off >>= 1) m = fmaxf(m, __shfl_xor(m, off));
    if ((t & 63) == 0) red_m[t >> 6] = m;
    __syncthreads();
    float mb = red_m[0];
#pragma unroll
    for (int k = 1; k < 16; ++k) mb = fmaxf(mb, red_m[k]);
    float s = 0.f;
    for (int i = t; i < NN; i += 1024) s += expf(scores[b * NN + i] - mb);
#pragma unroll
    for (int off = 32; off > 0; off >>= 1) s += __shfl_xor(s, off);
    if ((t & 63) == 0) red_s[t >> 6] = s;
    __syncthreads();
    if (t == 0) {
        float tot = 0.f;
#pragma unroll
        for (int k = 0; k < 16; ++k) tot += red_s[k];
        stats[b] = mb;
        stats[16 + b] = 1.f / tot;
    }
    if (t < CC) out[b * CC + t] = 0.f;
}

// ---------------- K3: out[b][c] += sum_n p_n * y[b][n][c] --------------------
__global__ __launch_bounds__(256) void k_out(const float* __restrict__ scores,
                                             const float* __restrict__ sy,
                                             const float* __restrict__ stats,
                                             float* __restrict__ out) {
    int b  = blockIdx.y;
    int n0 = blockIdx.x * 128;
    int t  = threadIdx.x;
    __shared__ float pl[128];
    __shared__ float red2[128];
    float mb = stats[b], inv = stats[16 + b];
    if (t < 128) pl[t] = expf(scores[b * NN + n0 + t] - mb) * inv;
    __syncthreads();
    int c = t & 127, rp = t >> 7;
    float acc = 0.f;
    if (c < CC) {
        const float* Y = sy + ((size_t)(b * NN + n0 + rp)) * CC + c;
#pragma unroll 4
        for (int r = 0; r < 64; ++r) acc += pl[rp + 2 * r] * Y[(size_t)(2 * CC) * r];
    }
    if (rp) red2[c] = acc;
    __syncthreads();
    if (!rp && c < CC) atomicAdd(&out[b * CC + c], acc + red2[c]);
}

extern "C" void kernel_launch(void* const* d_in, const int* in_sizes, int n_in,
                              void* d_out, int out_size, void* d_ws, size_t ws_size,
                              hipStream_t stream) {
    const float* x    = (const float*)d_in[0];   // (16,512)
    const float* sx   = (const float*)d_in[1];   // (16,8192,512)
    const float* sy   = (const float*)d_in[2];   // (16,8192,100)
    const float* W    = (const float*)d_in[3];   // (512,128)
    const float* mask = (const float*)d_in[4];   // (128,)
    float* out = (float*)d_out;
    char* ws = (char*)d_ws;
    ushort* Pth   = (ushort*)(ws + WSB_PTH);
    ushort* Ptl   = (ushort*)(ws + WSB_PTL);
    float*  qp    = (float*)(ws + WSB_QP);
    float*  scores= (float*)(ws + WSB_SC);
    float*  stats = (float*)(ws + WSB_ST);

    k_prep2 <<<64, 256, 0, stream>>>(W, mask, Pth, Ptl);
    k_q     <<<BB, 256, 0, stream>>>(x, W, mask, qp);
    k_scores<<<dim3(NN / 128, BB), 256, 0, stream>>>(sx, Pth, Ptl, qp, scores);
    k_stats <<<BB, 1024, 0, stream>>>(scores, stats, out);
    k_out   <<<dim3(NN / 128, BB), 256, 0, stream>>>(scores, sy, stats, out);
}